// Round 2
// baseline (381.128 us; speedup 1.0000x reference)
//
#include <hip/hip_runtime.h>
#include <hip/hip_bf16.h>

constexpr int PAD_T = 10, BOS_T = 11, EOS_T = 12, ROW_T = 13, SEP_T = 14;
constexpr int Bc = 16, Tc = 4096, Dc = 512;
constexpr int MAXH = 30, MAXW = 30;

typedef float fvec4 __attribute__((ext_vector_type(4)));

// Scratch in module-scope device globals (the d_ws poison is unconditional,
// so d_ws is unused entirely). scan_pre_kernel fully rewrites all three
// every launch before fuse_ln_kernel reads them: no stale-data hazard.
__device__ __align__(16) int   g_packed[Bc * Tc];        // 256 KiB
__device__ __align__(16) float g_frow[MAXH * Dc];        // 60 KiB
__device__ __align__(16) float g_fcol[MAXW * Dc];        // 60 KiB

// Composable transition summary of a token chunk.
struct Summ { int r, c0, c1, g0, g1, rk, ck; };

__device__ inline void tok_update(int tok, Summ& s) {
    if (tok == BOS_T)      { s.g0 = 1; s.g1 = 1; s.r = 0; s.c0 = 0; s.c1 = 0; s.rk = 0; s.ck = 0; }
    else if (tok == SEP_T) { s.r = 0; s.c0 = 0; s.c1 = 0; s.rk = 0; s.ck = 0; }
    else if (tok == ROW_T) { s.r += 1; s.c0 = 0; s.c1 = 0; s.ck = 0; }
    else if (tok == EOS_T || tok == PAD_T) { s.g0 = 0; s.g1 = 0; }
    else { s.c0 += s.g0; s.c1 += s.g1; }   // digit 0..9
}

__device__ inline Summ compose(const Summ& a, const Summ& b) {
    Summ o;
    o.g0 = a.g0 ? b.g1 : b.g0;
    o.g1 = a.g1 ? b.g1 : b.g0;
    o.r  = b.rk ? a.r + b.r : b.r;
    o.rk = a.rk & b.rk;
    int cm0 = a.g0 ? b.c1 : b.c0;
    int cm1 = a.g1 ? b.c1 : b.c0;
    o.c0 = b.ck ? a.c0 + cm0 : cm0;
    o.c1 = b.ck ? a.c1 + cm1 : cm1;
    o.ck = a.ck & b.ck;
    return o;
}

__device__ inline void apply_state(const Summ& s, int& r, int& c, int& g) {
    int cm = g ? s.c1 : s.c0;
    r = s.rk ? r + s.r : s.r;
    c = s.ck ? c + cm : cm;
    g = g ? s.g1 : s.g0;
}

// ---------------------------------------------------------------------------
// Dispatch 1 (merged): blocks 0..15 = parallel automaton scan; blocks 16..75 =
// einsum collapse Frow = row_table @ W[:, :256]^T, Fcol = col_table @ W[:, 256:]^T.
// Einsum now split-k across all 1024 threads (was 512 working / 512 idle).
// ---------------------------------------------------------------------------
__global__ __launch_bounds__(1024) void scan_pre_kernel(
        const int* __restrict__ ids,
        const float* __restrict__ row_table, const float* __restrict__ col_table,
        const float* __restrict__ w) {
    if (blockIdx.x < 16) {
        const int b = blockIdx.x;
        const int tid = threadIdx.x;          // 0..1023
        const int lane = tid & 63, wid = tid >> 6;

        const int4 tk4 = *(const int4*)(ids + b * Tc + tid * 4);
        int tks[4] = {tk4.x, tk4.y, tk4.z, tk4.w};

        Summ s{0, 0, 0, 0, 1, 1, 1};
#pragma unroll
        for (int j = 0; j < 4; ++j) tok_update(tks[j], s);

        Summ inc = s;
#pragma unroll
        for (int d = 1; d < 64; d <<= 1) {
            Summ o;
            o.r  = __shfl_up(inc.r, d);
            o.c0 = __shfl_up(inc.c0, d);
            o.c1 = __shfl_up(inc.c1, d);
            o.g0 = __shfl_up(inc.g0, d);
            o.g1 = __shfl_up(inc.g1, d);
            o.rk = __shfl_up(inc.rk, d);
            o.ck = __shfl_up(inc.ck, d);
            if (lane >= d) inc = compose(o, inc);
        }

        __shared__ int lsum[16][7];
        if (lane == 63) {
            lsum[wid][0] = inc.r;  lsum[wid][1] = inc.c0; lsum[wid][2] = inc.c1;
            lsum[wid][3] = inc.g0; lsum[wid][4] = inc.g1;
            lsum[wid][5] = inc.rk; lsum[wid][6] = inc.ck;
        }
        __syncthreads();

        int wr = 0, wc = 0, wg = 0;
        for (int w2 = 0; w2 < wid; ++w2) {
            Summ t;
            t.r  = lsum[w2][0]; t.c0 = lsum[w2][1]; t.c1 = lsum[w2][2];
            t.g0 = lsum[w2][3]; t.g1 = lsum[w2][4];
            t.rk = lsum[w2][5]; t.ck = lsum[w2][6];
            apply_state(t, wr, wc, wg);
        }

        Summ ex;
        ex.r  = __shfl_up(inc.r, 1);  ex.c0 = __shfl_up(inc.c0, 1);
        ex.c1 = __shfl_up(inc.c1, 1); ex.g0 = __shfl_up(inc.g0, 1);
        ex.g1 = __shfl_up(inc.g1, 1); ex.rk = __shfl_up(inc.rk, 1);
        ex.ck = __shfl_up(inc.ck, 1);
        if (lane == 0) { ex = Summ{0, 0, 0, 0, 1, 1, 1}; }
        int row = wr, col = wc, grid = wg;
        apply_state(ex, row, col, grid);

        int o4[4];
#pragma unroll
        for (int j = 0; j < 4; ++j) {
            int tok = tks[j];
            int gc = grid & (tok <= 9);
            int er = gc ? min(row, MAXH - 1) : 0;
            int ec = gc ? min(col, MAXW - 1) : 0;
            o4[j] = (er << 5) | ec;
            if (tok == BOS_T)      { grid = 1; row = 0; col = 0; }
            else if (tok == SEP_T) { row = 0; col = 0; }
            else if (tok == ROW_T) { row += 1; col = 0; }
            else if (tok == EOS_T || tok == PAD_T) { grid = 0; }
            else { col += gc; }
        }
        *(int4*)(g_packed + b * Tc + tid * 4) = make_int4(o4[0], o4[1], o4[2], o4[3]);
    } else {
        const int blk = blockIdx.x - 16;
        const int which = blk / 30;            // 0 -> Frow, 1 -> Fcol
        const int rr = blk % 30;
        const float* src = which ? (col_table + rr * 256) : (row_table + rr * 256);
        float* dst = which ? (g_fcol + rr * Dc) : (g_frow + rr * Dc);
        const int doff = which ? 256 : 0;

        __shared__ __align__(16) float sv[256];
        __shared__ float part[512];
        if (threadIdx.x < 256) sv[threadIdx.x] = src[threadIdx.x];
        __syncthreads();

        const int e    = threadIdx.x & 511;
        const int half = threadIdx.x >> 9;     // split-k: 2 threads per output
        const float4* a4 = (const float4*)sv + half * 32;
        const float4* w4 = (const float4*)(w + (size_t)e * Dc + doff) + half * 32;
        float acc = 0.f;
#pragma unroll 8
        for (int k = 0; k < 32; ++k) {
            float4 a = a4[k];
            float4 wb = w4[k];
            acc += a.x * wb.x + a.y * wb.y + a.z * wb.z + a.w * wb.w;
        }
        if (half) part[e] = acc;
        __syncthreads();
        if (!half) dst[e] = acc + part[e];
    }
}

// ---------------------------------------------------------------------------
// Dispatch 2: fused embed-add + LayerNorm. Block = one timestep t (4096
// blocks); 4 waves x 4 tokens/wave. Each wave packs 2 tokens per 32-lane
// half (16 elems/lane): butterfly is 5 levels instead of 6 and serves 2
// tokens per shfl -> 58% fewer DS ops/token. pos/gamma/beta amortized over
// 4 tokens. Spatial add predicated (fm in {0,1}) to avoid half-wave
// divergence; frow/fcol are L2-resident (120 KiB) so dead loads are cheap.
// ---------------------------------------------------------------------------
__global__ __launch_bounds__(256) void fuse_ln_kernel(
        const int* __restrict__ ids,
        const float* __restrict__ token_table, const float* __restrict__ pos_table,
        const float* __restrict__ gamma, const float* __restrict__ beta,
        float* __restrict__ out) {
    const int t    = blockIdx.x;              // one block per timestep
    const int wave = threadIdx.x >> 6;
    const int lane = threadIdx.x & 63;
    const int h    = lane >> 5;               // half: token select
    const int d0   = (lane & 31) * 16;        // 16 elems per lane, 32 lanes = 512
    const int bb0  = wave * 4;                // this wave's 4 batch rows

    int tok[4], pk[4];
#pragma unroll
    for (int k = 0; k < 4; ++k) {
        tok[k] = ids[(bb0 + k) * Tc + t];
        pk[k]  = g_packed[(bb0 + k) * Tc + t];
    }

    float xp[16];
    {
        const float* p = pos_table + (size_t)t * Dc + d0;
#pragma unroll
        for (int q = 0; q < 4; ++q) *(float4*)(xp + 4 * q) = *(const float4*)(p + 4 * q);
    }

    float xA[16], xB[16];
    float sA = 0.f, qA = 0.f, sB = 0.f, qB = 0.f;

    // ---- pair 0: tokens bb0+0 (h=0) / bb0+1 (h=1) ----
    {
        const int tokp = h ? tok[1] : tok[0];
        const int pkp  = h ? pk[1]  : pk[0];
        const float* tr = token_table + (size_t)tokp * Dc + d0;
#pragma unroll
        for (int q = 0; q < 4; ++q) {
            float4 v = *(const float4*)(tr + 4 * q);
            xA[4 * q + 0] = v.x + xp[4 * q + 0];
            xA[4 * q + 1] = v.y + xp[4 * q + 1];
            xA[4 * q + 2] = v.z + xp[4 * q + 2];
            xA[4 * q + 3] = v.w + xp[4 * q + 3];
        }
        const bool dig = (tokp <= 9);
        if (__any(dig)) {
            const float fm = dig ? 1.f : 0.f;
            const int rI = dig ? (pkp >> 5) : 0;
            const int cI = dig ? (pkp & 31) : 0;
            const float* fr = g_frow + (size_t)rI * Dc + d0;
            const float* fc = g_fcol + (size_t)cI * Dc + d0;
#pragma unroll
            for (int q = 0; q < 4; ++q) {
                float4 a = *(const float4*)(fr + 4 * q);
                float4 b = *(const float4*)(fc + 4 * q);
                xA[4 * q + 0] = fmaf(fm, a.x + b.x, xA[4 * q + 0]);
                xA[4 * q + 1] = fmaf(fm, a.y + b.y, xA[4 * q + 1]);
                xA[4 * q + 2] = fmaf(fm, a.z + b.z, xA[4 * q + 2]);
                xA[4 * q + 3] = fmaf(fm, a.w + b.w, xA[4 * q + 3]);
            }
        }
#pragma unroll
        for (int j = 0; j < 16; ++j) { sA += xA[j]; qA = fmaf(xA[j], xA[j], qA); }
    }

    // ---- pair 1: tokens bb0+2 (h=0) / bb0+3 (h=1) ----
    {
        const int tokp = h ? tok[3] : tok[2];
        const int pkp  = h ? pk[3]  : pk[2];
        const float* tr = token_table + (size_t)tokp * Dc + d0;
#pragma unroll
        for (int q = 0; q < 4; ++q) {
            float4 v = *(const float4*)(tr + 4 * q);
            xB[4 * q + 0] = v.x + xp[4 * q + 0];
            xB[4 * q + 1] = v.y + xp[4 * q + 1];
            xB[4 * q + 2] = v.z + xp[4 * q + 2];
            xB[4 * q + 3] = v.w + xp[4 * q + 3];
        }
        const bool dig = (tokp <= 9);
        if (__any(dig)) {
            const float fm = dig ? 1.f : 0.f;
            const int rI = dig ? (pkp >> 5) : 0;
            const int cI = dig ? (pkp & 31) : 0;
            const float* fr = g_frow + (size_t)rI * Dc + d0;
            const float* fc = g_fcol + (size_t)cI * Dc + d0;
#pragma unroll
            for (int q = 0; q < 4; ++q) {
                float4 a = *(const float4*)(fr + 4 * q);
                float4 b = *(const float4*)(fc + 4 * q);
                xB[4 * q + 0] = fmaf(fm, a.x + b.x, xB[4 * q + 0]);
                xB[4 * q + 1] = fmaf(fm, a.y + b.y, xB[4 * q + 1]);
                xB[4 * q + 2] = fmaf(fm, a.z + b.z, xB[4 * q + 2]);
                xB[4 * q + 3] = fmaf(fm, a.w + b.w, xB[4 * q + 3]);
            }
        }
#pragma unroll
        for (int j = 0; j < 16; ++j) { sB += xB[j]; qB = fmaf(xB[j], xB[j], qB); }
    }

    // 5-level butterfly within each 32-lane half (xor mask < 32 stays in-half),
    // two pairs interleaved for ILP.
#pragma unroll
    for (int m = 1; m < 32; m <<= 1) {
        sA += __shfl_xor(sA, m);
        sB += __shfl_xor(sB, m);
        qA += __shfl_xor(qA, m);
        qB += __shfl_xor(qB, m);
    }

    const float muA  = sA * (1.0f / Dc);
    const float muB  = sB * (1.0f / Dc);
    const float varA = fmaf(-muA, muA, qA * (1.0f / Dc));
    const float varB = fmaf(-muB, muB, qB * (1.0f / Dc));
    const float invA = rsqrtf(varA + 1e-5f);
    const float invB = rsqrtf(varB + 1e-5f);

    float gm[16], bt[16];
#pragma unroll
    for (int q = 0; q < 4; ++q) {
        *(float4*)(gm + 4 * q) = *(const float4*)(gamma + d0 + 4 * q);
        *(float4*)(bt + 4 * q) = *(const float4*)(beta  + d0 + 4 * q);
    }

    {   // store pair 0: b = bb0 + h
        float* op = out + ((size_t)((bb0 + h) * Tc + t)) * Dc + d0;
#pragma unroll
        for (int q = 0; q < 4; ++q) {
            fvec4 y;
            y.x = fmaf((xA[4 * q + 0] - muA) * invA, gm[4 * q + 0], bt[4 * q + 0]);
            y.y = fmaf((xA[4 * q + 1] - muA) * invA, gm[4 * q + 1], bt[4 * q + 1]);
            y.z = fmaf((xA[4 * q + 2] - muA) * invA, gm[4 * q + 2], bt[4 * q + 2]);
            y.w = fmaf((xA[4 * q + 3] - muA) * invA, gm[4 * q + 3], bt[4 * q + 3]);
            __builtin_nontemporal_store(y, (fvec4*)(op + 4 * q));
        }
    }
    {   // store pair 1: b = bb0 + 2 + h
        float* op = out + ((size_t)((bb0 + 2 + h) * Tc + t)) * Dc + d0;
#pragma unroll
        for (int q = 0; q < 4; ++q) {
            fvec4 y;
            y.x = fmaf((xB[4 * q + 0] - muB) * invB, gm[4 * q + 0], bt[4 * q + 0]);
            y.y = fmaf((xB[4 * q + 1] - muB) * invB, gm[4 * q + 1], bt[4 * q + 1]);
            y.z = fmaf((xB[4 * q + 2] - muB) * invB, gm[4 * q + 2], bt[4 * q + 2]);
            y.w = fmaf((xB[4 * q + 3] - muB) * invB, gm[4 * q + 3], bt[4 * q + 3]);
            __builtin_nontemporal_store(y, (fvec4*)(op + 4 * q));
        }
    }
}

extern "C" void kernel_launch(void* const* d_in, const int* in_sizes, int n_in,
                              void* d_out, int out_size, void* d_ws, size_t ws_size,
                              hipStream_t stream) {
    const int*   ids         = (const int*)d_in[0];
    const float* token_table = (const float*)d_in[1];
    const float* pos_table   = (const float*)d_in[2];
    const float* row_table   = (const float*)d_in[3];
    const float* col_table   = (const float*)d_in[4];
    const float* w_spatial   = (const float*)d_in[5];
    const float* ln_gamma    = (const float*)d_in[6];
    const float* ln_beta     = (const float*)d_in[7];
    float* out = (float*)d_out;

    (void)d_ws; (void)ws_size;   // ws poison is unconditional; we don't add to it

    hipLaunchKernelGGL(scan_pre_kernel, dim3(76), dim3(1024), 0, stream,
                       ids, row_table, col_table, w_spatial);
    hipLaunchKernelGGL(fuse_ln_kernel, dim3(Tc), dim3(256), 0, stream,
                       ids, token_table, pos_table, ln_gamma, ln_beta, out);
}

// Round 3
// 194.878 us; speedup vs baseline: 1.9557x; 1.9557x over previous
//
#include <hip/hip_runtime.h>
#include <hip/hip_bf16.h>

constexpr int PAD_T = 10, BOS_T = 11, EOS_T = 12, ROW_T = 13, SEP_T = 14;
constexpr int Bc = 16, Tc = 4096, Dc = 512;
constexpr int MAXH = 30, MAXW = 30;

typedef float fvec4 __attribute__((ext_vector_type(4)));

// Scratch in module-scope device globals (the d_ws poison is unconditional,
// so d_ws is unused entirely). scan_pre_kernel fully rewrites all three
// every launch before fuse_ln_kernel reads them: no stale-data hazard.
__device__ __align__(16) int   g_packed[Bc * Tc];        // 256 KiB
__device__ __align__(16) float g_frow[MAXH * Dc];        // 60 KiB
__device__ __align__(16) float g_fcol[MAXW * Dc];        // 60 KiB

// Composable transition summary of a token chunk.
struct Summ { int r, c0, c1, g0, g1, rk, ck; };

__device__ inline void tok_update(int tok, Summ& s) {
    if (tok == BOS_T)      { s.g0 = 1; s.g1 = 1; s.r = 0; s.c0 = 0; s.c1 = 0; s.rk = 0; s.ck = 0; }
    else if (tok == SEP_T) { s.r = 0; s.c0 = 0; s.c1 = 0; s.rk = 0; s.ck = 0; }
    else if (tok == ROW_T) { s.r += 1; s.c0 = 0; s.c1 = 0; s.ck = 0; }
    else if (tok == EOS_T || tok == PAD_T) { s.g0 = 0; s.g1 = 0; }
    else { s.c0 += s.g0; s.c1 += s.g1; }   // digit 0..9
}

__device__ inline Summ compose(const Summ& a, const Summ& b) {
    Summ o;
    o.g0 = a.g0 ? b.g1 : b.g0;
    o.g1 = a.g1 ? b.g1 : b.g0;
    o.r  = b.rk ? a.r + b.r : b.r;
    o.rk = a.rk & b.rk;
    int cm0 = a.g0 ? b.c1 : b.c0;
    int cm1 = a.g1 ? b.c1 : b.c0;
    o.c0 = b.ck ? a.c0 + cm0 : cm0;
    o.c1 = b.ck ? a.c1 + cm1 : cm1;
    o.ck = a.ck & b.ck;
    return o;
}

__device__ inline void apply_state(const Summ& s, int& r, int& c, int& g) {
    int cm = g ? s.c1 : s.c0;
    r = s.rk ? r + s.r : s.r;
    c = s.ck ? c + cm : cm;
    g = g ? s.g1 : s.g0;
}

// ---------------------------------------------------------------------------
// Dispatch 1 (merged): blocks 0..15 = parallel automaton scan; blocks 16..75 =
// einsum collapse Frow = row_table @ W[:, :256]^T, Fcol = col_table @ W[:, 256:]^T.
// Einsum split-k across all 1024 threads.
// ---------------------------------------------------------------------------
__global__ __launch_bounds__(1024) void scan_pre_kernel(
        const int* __restrict__ ids,
        const float* __restrict__ row_table, const float* __restrict__ col_table,
        const float* __restrict__ w) {
    if (blockIdx.x < 16) {
        const int b = blockIdx.x;
        const int tid = threadIdx.x;          // 0..1023
        const int lane = tid & 63, wid = tid >> 6;

        const int4 tk4 = *(const int4*)(ids + b * Tc + tid * 4);
        int tks[4] = {tk4.x, tk4.y, tk4.z, tk4.w};

        Summ s{0, 0, 0, 0, 1, 1, 1};
#pragma unroll
        for (int j = 0; j < 4; ++j) tok_update(tks[j], s);

        Summ inc = s;
#pragma unroll
        for (int d = 1; d < 64; d <<= 1) {
            Summ o;
            o.r  = __shfl_up(inc.r, d);
            o.c0 = __shfl_up(inc.c0, d);
            o.c1 = __shfl_up(inc.c1, d);
            o.g0 = __shfl_up(inc.g0, d);
            o.g1 = __shfl_up(inc.g1, d);
            o.rk = __shfl_up(inc.rk, d);
            o.ck = __shfl_up(inc.ck, d);
            if (lane >= d) inc = compose(o, inc);
        }

        __shared__ int lsum[16][7];
        if (lane == 63) {
            lsum[wid][0] = inc.r;  lsum[wid][1] = inc.c0; lsum[wid][2] = inc.c1;
            lsum[wid][3] = inc.g0; lsum[wid][4] = inc.g1;
            lsum[wid][5] = inc.rk; lsum[wid][6] = inc.ck;
        }
        __syncthreads();

        int wr = 0, wc = 0, wg = 0;
        for (int w2 = 0; w2 < wid; ++w2) {
            Summ t;
            t.r  = lsum[w2][0]; t.c0 = lsum[w2][1]; t.c1 = lsum[w2][2];
            t.g0 = lsum[w2][3]; t.g1 = lsum[w2][4];
            t.rk = lsum[w2][5]; t.ck = lsum[w2][6];
            apply_state(t, wr, wc, wg);
        }

        Summ ex;
        ex.r  = __shfl_up(inc.r, 1);  ex.c0 = __shfl_up(inc.c0, 1);
        ex.c1 = __shfl_up(inc.c1, 1); ex.g0 = __shfl_up(inc.g0, 1);
        ex.g1 = __shfl_up(inc.g1, 1); ex.rk = __shfl_up(inc.rk, 1);
        ex.ck = __shfl_up(inc.ck, 1);
        if (lane == 0) { ex = Summ{0, 0, 0, 0, 1, 1, 1}; }
        int row = wr, col = wc, grid = wg;
        apply_state(ex, row, col, grid);

        int o4[4];
#pragma unroll
        for (int j = 0; j < 4; ++j) {
            int tok = tks[j];
            int gc = grid & (tok <= 9);
            int er = gc ? min(row, MAXH - 1) : 0;
            int ec = gc ? min(col, MAXW - 1) : 0;
            o4[j] = (er << 5) | ec;
            if (tok == BOS_T)      { grid = 1; row = 0; col = 0; }
            else if (tok == SEP_T) { row = 0; col = 0; }
            else if (tok == ROW_T) { row += 1; col = 0; }
            else if (tok == EOS_T || tok == PAD_T) { grid = 0; }
            else { col += gc; }
        }
        *(int4*)(g_packed + b * Tc + tid * 4) = make_int4(o4[0], o4[1], o4[2], o4[3]);
    } else {
        const int blk = blockIdx.x - 16;
        const int which = blk / 30;            // 0 -> Frow, 1 -> Fcol
        const int rr = blk % 30;
        const float* src = which ? (col_table + rr * 256) : (row_table + rr * 256);
        float* dst = which ? (g_fcol + rr * Dc) : (g_frow + rr * Dc);
        const int doff = which ? 256 : 0;

        __shared__ __align__(16) float sv[256];
        __shared__ float part[512];
        if (threadIdx.x < 256) sv[threadIdx.x] = src[threadIdx.x];
        __syncthreads();

        const int e    = threadIdx.x & 511;
        const int half = threadIdx.x >> 9;     // split-k: 2 threads per output
        const float4* a4 = (const float4*)sv + half * 32;
        const float4* w4 = (const float4*)(w + (size_t)e * Dc + doff) + half * 32;
        float acc = 0.f;
#pragma unroll 8
        for (int k = 0; k < 32; ++k) {
            float4 a = a4[k];
            float4 wb = w4[k];
            acc += a.x * wb.x + a.y * wb.y + a.z * wb.z + a.w * wb.w;
        }
        if (half) part[e] = acc;
        __syncthreads();
        if (!half) dst[e] = acc + part[e];
    }
}

// ---------------------------------------------------------------------------
// Dispatch 2: fused embed-add + LayerNorm. TWO tokens per wave (same t,
// b and b+8). d0 = lane*8: full-wave 2KB-contiguous store footprint.
// PLAIN cached stores (not nontemporal): round-2 measured 2.3x HBM write
// amplification from NT partial-sector stores; L2 write-back merges the
// interleaved 16B partials into full lines.
// ---------------------------------------------------------------------------
__global__ __launch_bounds__(256) void fuse_ln_kernel(
        const int* __restrict__ ids,
        const float* __restrict__ token_table, const float* __restrict__ pos_table,
        const float* __restrict__ gamma, const float* __restrict__ beta,
        float* __restrict__ out) {
    const int wave = threadIdx.x >> 6;
    const int lane = threadIdx.x & 63;
    const int g2 = blockIdx.x * 4 + wave;    // [0, 8*T): (t, b0) with b0 in [0,8)
    const int b0 = g2 & 7;
    const int t  = g2 >> 3;
    const int idx0 = b0 * Tc + t;
    const int idx1 = idx0 + 8 * Tc;
    const int d0 = lane * 8;

    const int tok0 = ids[idx0];
    const int tok1 = ids[idx1];
    const int pk0 = g_packed[idx0];
    const int pk1 = g_packed[idx1];

    float xp[8];
    *(float4*)(xp + 0) = *(const float4*)(pos_table + (size_t)t * Dc + d0);
    *(float4*)(xp + 4) = *(const float4*)(pos_table + (size_t)t * Dc + d0 + 4);

    float x0[8], x1[8];
    {
        float xt[8];
        *(float4*)(xt + 0) = *(const float4*)(token_table + (size_t)tok0 * Dc + d0);
        *(float4*)(xt + 4) = *(const float4*)(token_table + (size_t)tok0 * Dc + d0 + 4);
#pragma unroll
        for (int j = 0; j < 8; ++j) x0[j] = xt[j] + xp[j];
    }
    {
        float xt[8];
        *(float4*)(xt + 0) = *(const float4*)(token_table + (size_t)tok1 * Dc + d0);
        *(float4*)(xt + 4) = *(const float4*)(token_table + (size_t)tok1 * Dc + d0 + 4);
#pragma unroll
        for (int j = 0; j < 8; ++j) x1[j] = xt[j] + xp[j];
    }

    if (tok0 <= 9) {                         // wave-uniform
        const int rI = pk0 >> 5, cI = pk0 & 31;
        float xf[8], xc[8];
        *(float4*)(xf + 0) = *(const float4*)(g_frow + (size_t)rI * Dc + d0);
        *(float4*)(xf + 4) = *(const float4*)(g_frow + (size_t)rI * Dc + d0 + 4);
        *(float4*)(xc + 0) = *(const float4*)(g_fcol + (size_t)cI * Dc + d0);
        *(float4*)(xc + 4) = *(const float4*)(g_fcol + (size_t)cI * Dc + d0 + 4);
#pragma unroll
        for (int j = 0; j < 8; ++j) x0[j] += xf[j] + xc[j];
    }
    if (tok1 <= 9) {                         // wave-uniform
        const int rI = pk1 >> 5, cI = pk1 & 31;
        float xf[8], xc[8];
        *(float4*)(xf + 0) = *(const float4*)(g_frow + (size_t)rI * Dc + d0);
        *(float4*)(xf + 4) = *(const float4*)(g_frow + (size_t)rI * Dc + d0 + 4);
        *(float4*)(xc + 0) = *(const float4*)(g_fcol + (size_t)cI * Dc + d0);
        *(float4*)(xc + 4) = *(const float4*)(g_fcol + (size_t)cI * Dc + d0 + 4);
#pragma unroll
        for (int j = 0; j < 8; ++j) x1[j] += xf[j] + xc[j];
    }

    float s0 = 0.f, q0 = 0.f, s1 = 0.f, q1 = 0.f;
#pragma unroll
    for (int j = 0; j < 8; ++j) {
        s0 += x0[j]; q0 = fmaf(x0[j], x0[j], q0);
        s1 += x1[j]; q1 = fmaf(x1[j], x1[j], q1);
    }
    // two independent butterfly reductions, interleaved for ILP
#pragma unroll
    for (int m = 1; m < 64; m <<= 1) {
        s0 += __shfl_xor(s0, m);
        s1 += __shfl_xor(s1, m);
        q0 += __shfl_xor(q0, m);
        q1 += __shfl_xor(q1, m);
    }
    const float mu0  = s0 * (1.0f / Dc);
    const float mu1  = s1 * (1.0f / Dc);
    const float var0 = fmaf(-mu0, mu0, q0 * (1.0f / Dc));
    const float var1 = fmaf(-mu1, mu1, q1 * (1.0f / Dc));
    const float inv0 = rsqrtf(var0 + 1e-5f);
    const float inv1 = rsqrtf(var1 + 1e-5f);

    float gm[8], bb[8];
    *(float4*)(gm + 0) = *(const float4*)(gamma + d0);
    *(float4*)(gm + 4) = *(const float4*)(gamma + d0 + 4);
    *(float4*)(bb + 0) = *(const float4*)(beta + d0);
    *(float4*)(bb + 4) = *(const float4*)(beta + d0 + 4);

    fvec4 y0a, y0b, y1a, y1b;
    y0a.x = fmaf((x0[0] - mu0) * inv0, gm[0], bb[0]);
    y0a.y = fmaf((x0[1] - mu0) * inv0, gm[1], bb[1]);
    y0a.z = fmaf((x0[2] - mu0) * inv0, gm[2], bb[2]);
    y0a.w = fmaf((x0[3] - mu0) * inv0, gm[3], bb[3]);
    y0b.x = fmaf((x0[4] - mu0) * inv0, gm[4], bb[4]);
    y0b.y = fmaf((x0[5] - mu0) * inv0, gm[5], bb[5]);
    y0b.z = fmaf((x0[6] - mu0) * inv0, gm[6], bb[6]);
    y0b.w = fmaf((x0[7] - mu0) * inv0, gm[7], bb[7]);
    y1a.x = fmaf((x1[0] - mu1) * inv1, gm[0], bb[0]);
    y1a.y = fmaf((x1[1] - mu1) * inv1, gm[1], bb[1]);
    y1a.z = fmaf((x1[2] - mu1) * inv1, gm[2], bb[2]);
    y1a.w = fmaf((x1[3] - mu1) * inv1, gm[3], bb[3]);
    y1b.x = fmaf((x1[4] - mu1) * inv1, gm[4], bb[4]);
    y1b.y = fmaf((x1[5] - mu1) * inv1, gm[5], bb[5]);
    y1b.z = fmaf((x1[6] - mu1) * inv1, gm[6], bb[6]);
    y1b.w = fmaf((x1[7] - mu1) * inv1, gm[7], bb[7]);

    float* op0 = out + (size_t)idx0 * Dc + d0;
    float* op1 = out + (size_t)idx1 * Dc + d0;
    *(fvec4*)(op0 + 0) = y0a;
    *(fvec4*)(op0 + 4) = y0b;
    *(fvec4*)(op1 + 0) = y1a;
    *(fvec4*)(op1 + 4) = y1b;
}

extern "C" void kernel_launch(void* const* d_in, const int* in_sizes, int n_in,
                              void* d_out, int out_size, void* d_ws, size_t ws_size,
                              hipStream_t stream) {
    const int*   ids         = (const int*)d_in[0];
    const float* token_table = (const float*)d_in[1];
    const float* pos_table   = (const float*)d_in[2];
    const float* row_table   = (const float*)d_in[3];
    const float* col_table   = (const float*)d_in[4];
    const float* w_spatial   = (const float*)d_in[5];
    const float* ln_gamma    = (const float*)d_in[6];
    const float* ln_beta     = (const float*)d_in[7];
    float* out = (float*)d_out;

    (void)d_ws; (void)ws_size;   // ws poison is unconditional; we don't add to it

    hipLaunchKernelGGL(scan_pre_kernel, dim3(76), dim3(1024), 0, stream,
                       ids, row_table, col_table, w_spatial);
    hipLaunchKernelGGL(fuse_ln_kernel, dim3(Bc * Tc / 8), dim3(256), 0, stream,
                       ids, token_table, pos_table, ln_gamma, ln_beta, out);
}

// Round 5
// 190.134 us; speedup vs baseline: 2.0045x; 1.0250x over previous
//
#include <hip/hip_runtime.h>
#include <hip/hip_bf16.h>

constexpr int PAD_T = 10, BOS_T = 11, EOS_T = 12, ROW_T = 13, SEP_T = 14;
constexpr int Bc = 16, Tc = 4096, Dc = 512;
constexpr int MAXH = 30, MAXW = 30;

typedef float fvec4 __attribute__((ext_vector_type(4)));

// Scratch in module-scope device globals (the d_ws poison is unconditional,
// so d_ws is unused entirely). scan_pre_kernel fully rewrites all three
// every launch before fuse_ln_kernel reads them: no stale-data hazard.
__device__ __align__(16) int   g_packed[Bc * Tc];        // 256 KiB
__device__ __align__(16) float g_frow[MAXH * Dc];        // 60 KiB
__device__ __align__(16) float g_fcol[MAXW * Dc];        // 60 KiB

// Composable transition summary of a token chunk.
struct Summ { int r, c0, c1, g0, g1, rk, ck; };

__device__ inline void tok_update(int tok, Summ& s) {
    if (tok == BOS_T)      { s.g0 = 1; s.g1 = 1; s.r = 0; s.c0 = 0; s.c1 = 0; s.rk = 0; s.ck = 0; }
    else if (tok == SEP_T) { s.r = 0; s.c0 = 0; s.c1 = 0; s.rk = 0; s.ck = 0; }
    else if (tok == ROW_T) { s.r += 1; s.c0 = 0; s.c1 = 0; s.ck = 0; }
    else if (tok == EOS_T || tok == PAD_T) { s.g0 = 0; s.g1 = 0; }
    else { s.c0 += s.g0; s.c1 += s.g1; }   // digit 0..9
}

__device__ inline Summ compose(const Summ& a, const Summ& b) {
    Summ o;
    o.g0 = a.g0 ? b.g1 : b.g0;
    o.g1 = a.g1 ? b.g1 : b.g0;
    o.r  = b.rk ? a.r + b.r : b.r;
    o.rk = a.rk & b.rk;
    int cm0 = a.g0 ? b.c1 : b.c0;
    int cm1 = a.g1 ? b.c1 : b.c0;
    o.c0 = b.ck ? a.c0 + cm0 : cm0;
    o.c1 = b.ck ? a.c1 + cm1 : cm1;
    o.ck = a.ck & b.ck;
    return o;
}

__device__ inline void apply_state(const Summ& s, int& r, int& c, int& g) {
    int cm = g ? s.c1 : s.c0;
    r = s.rk ? r + s.r : s.r;
    c = s.ck ? c + cm : cm;
    g = g ? s.g1 : s.g0;
}

// ---------------------------------------------------------------------------
// Dispatch 1 (merged): blocks 0..15 = parallel automaton scan; blocks 16..75 =
// einsum collapse Frow = row_table @ W[:, :256]^T, Fcol = col_table @ W[:, 256:]^T.
// ---------------------------------------------------------------------------
__global__ __launch_bounds__(1024) void scan_pre_kernel(
        const int* __restrict__ ids,
        const float* __restrict__ row_table, const float* __restrict__ col_table,
        const float* __restrict__ w) {
    if (blockIdx.x < 16) {
        const int b = blockIdx.x;
        const int tid = threadIdx.x;          // 0..1023
        const int lane = tid & 63, wid = tid >> 6;

        const int4 tk4 = *(const int4*)(ids + b * Tc + tid * 4);
        int tks[4] = {tk4.x, tk4.y, tk4.z, tk4.w};

        Summ s{0, 0, 0, 0, 1, 1, 1};
#pragma unroll
        for (int j = 0; j < 4; ++j) tok_update(tks[j], s);

        Summ inc = s;
#pragma unroll
        for (int d = 1; d < 64; d <<= 1) {
            Summ o;
            o.r  = __shfl_up(inc.r, d);
            o.c0 = __shfl_up(inc.c0, d);
            o.c1 = __shfl_up(inc.c1, d);
            o.g0 = __shfl_up(inc.g0, d);
            o.g1 = __shfl_up(inc.g1, d);
            o.rk = __shfl_up(inc.rk, d);
            o.ck = __shfl_up(inc.ck, d);
            if (lane >= d) inc = compose(o, inc);
        }

        __shared__ int lsum[16][7];
        if (lane == 63) {
            lsum[wid][0] = inc.r;  lsum[wid][1] = inc.c0; lsum[wid][2] = inc.c1;
            lsum[wid][3] = inc.g0; lsum[wid][4] = inc.g1;
            lsum[wid][5] = inc.rk; lsum[wid][6] = inc.ck;
        }
        __syncthreads();

        int wr = 0, wc = 0, wg = 0;
        for (int w2 = 0; w2 < wid; ++w2) {
            Summ t;
            t.r  = lsum[w2][0]; t.c0 = lsum[w2][1]; t.c1 = lsum[w2][2];
            t.g0 = lsum[w2][3]; t.g1 = lsum[w2][4];
            t.rk = lsum[w2][5]; t.ck = lsum[w2][6];
            apply_state(t, wr, wc, wg);
        }

        Summ ex;
        ex.r  = __shfl_up(inc.r, 1);  ex.c0 = __shfl_up(inc.c0, 1);
        ex.c1 = __shfl_up(inc.c1, 1); ex.g0 = __shfl_up(inc.g0, 1);
        ex.g1 = __shfl_up(inc.g1, 1); ex.rk = __shfl_up(inc.rk, 1);
        ex.ck = __shfl_up(inc.ck, 1);
        if (lane == 0) { ex = Summ{0, 0, 0, 0, 1, 1, 1}; }
        int row = wr, col = wc, grid = wg;
        apply_state(ex, row, col, grid);

        int o4[4];
#pragma unroll
        for (int j = 0; j < 4; ++j) {
            int tok = tks[j];
            int gc = grid & (tok <= 9);
            int er = gc ? min(row, MAXH - 1) : 0;
            int ec = gc ? min(col, MAXW - 1) : 0;
            o4[j] = (er << 5) | ec;
            if (tok == BOS_T)      { grid = 1; row = 0; col = 0; }
            else if (tok == SEP_T) { row = 0; col = 0; }
            else if (tok == ROW_T) { row += 1; col = 0; }
            else if (tok == EOS_T || tok == PAD_T) { grid = 0; }
            else { col += gc; }
        }
        *(int4*)(g_packed + b * Tc + tid * 4) = make_int4(o4[0], o4[1], o4[2], o4[3]);
    } else {
        const int blk = blockIdx.x - 16;
        const int which = blk / 30;            // 0 -> Frow, 1 -> Fcol
        const int rr = blk % 30;
        const float* src = which ? (col_table + rr * 256) : (row_table + rr * 256);
        float* dst = which ? (g_fcol + rr * Dc) : (g_frow + rr * Dc);
        const int doff = which ? 256 : 0;

        __shared__ __align__(16) float sv[256];
        __shared__ float part[512];
        if (threadIdx.x < 256) sv[threadIdx.x] = src[threadIdx.x];
        __syncthreads();

        const int e    = threadIdx.x & 511;
        const int half = threadIdx.x >> 9;     // split-k: 2 threads per output
        const float4* a4 = (const float4*)sv + half * 32;
        const float4* w4 = (const float4*)(w + (size_t)e * Dc + doff) + half * 32;
        float acc = 0.f;
#pragma unroll 8
        for (int k = 0; k < 32; ++k) {
            float4 a = a4[k];
            float4 wb = w4[k];
            acc += a.x * wb.x + a.y * wb.y + a.z * wb.z + a.w * wb.w;
        }
        if (half) part[e] = acc;
        __syncthreads();
        if (!half) dst[e] = acc + part[e];
    }
}

// ---------------------------------------------------------------------------
// Dispatch 2: fused embed-add + LayerNorm. FOUR tokens per wave:
// (b0,t),(b0+8,t),(b0,t+1),(b0+8,t+1). Latency-bound regime (VALUBusy ~3%,
// HBM ~16%, occ ~48% from round-2 counters): double per-wave memory-level
// parallelism. ids/packed are 8B vector loads (2 tokens each); all 4 token
// rows' loads independent and in flight together; 8 butterfly chains
// interleaved; stores form two contiguous 4KB runs. Cached stores (NT
// amplifies HBM writes 2.3x: measured round 2).
// ---------------------------------------------------------------------------
__global__ __launch_bounds__(256) void fuse_ln_kernel(
        const int* __restrict__ ids,
        const float* __restrict__ token_table, const float* __restrict__ pos_table,
        const float* __restrict__ gamma, const float* __restrict__ beta,
        float* __restrict__ out) {
    const int wave = threadIdx.x >> 6;
    const int lane = threadIdx.x & 63;
    const int g2 = blockIdx.x * 4 + wave;    // (t-pair, b0), b0 in [0,8)
    const int b0 = g2 & 7;
    const int t  = (g2 >> 3) << 1;           // even t; wave covers t, t+1
    const int idx00 = b0 * Tc + t;           // (b0,   t)
    const int idx10 = idx00 + 8 * Tc;        // (b0+8, t)
    const int d0 = lane * 8;

    // token ids + packed coords: 8B vector loads, 2 tokens each, issued first
    const int2 tkA = *(const int2*)(ids + idx00);       // (b0,t), (b0,t+1)
    const int2 tkB = *(const int2*)(ids + idx10);       // (b0+8,t), (b0+8,t+1)
    const int2 pkA = *(const int2*)(g_packed + idx00);
    const int2 pkB = *(const int2*)(g_packed + idx10);

    // pos rows for t and t+1
    float xpA[8], xpB[8];
    {
        const float* p0 = pos_table + (size_t)t * Dc + d0;
        *(float4*)(xpA + 0) = *(const float4*)(p0);
        *(float4*)(xpA + 4) = *(const float4*)(p0 + 4);
        *(float4*)(xpB + 0) = *(const float4*)(p0 + Dc);
        *(float4*)(xpB + 4) = *(const float4*)(p0 + Dc + 4);
    }

    // gamma/beta (L1-resident after first block on a CU)
    float gm[8], bt[8];
    *(float4*)(gm + 0) = *(const float4*)(gamma + d0);
    *(float4*)(gm + 4) = *(const float4*)(gamma + d0 + 4);
    *(float4*)(bt + 0) = *(const float4*)(beta + d0);
    *(float4*)(bt + 4) = *(const float4*)(beta + d0 + 4);

    float x00[8], x01[8], x10[8], x11[8];

    auto load_tok = [&](float* dst, int tok, const float* xp) {
        const float* tr = token_table + (size_t)tok * Dc + d0;
        float4 va = *(const float4*)(tr);
        float4 vb = *(const float4*)(tr + 4);
        dst[0] = va.x + xp[0]; dst[1] = va.y + xp[1];
        dst[2] = va.z + xp[2]; dst[3] = va.w + xp[3];
        dst[4] = vb.x + xp[4]; dst[5] = vb.y + xp[5];
        dst[6] = vb.z + xp[6]; dst[7] = vb.w + xp[7];
    };
    load_tok(x00, tkA.x, xpA);
    load_tok(x01, tkA.y, xpB);
    load_tok(x10, tkB.x, xpA);
    load_tok(x11, tkB.y, xpB);

    auto add_spatial = [&](float* dst, int tok, int pk) {
        if (tok <= 9) {                      // wave-uniform branch
            const int rI = pk >> 5, cI = pk & 31;
            const float* fr = g_frow + (size_t)rI * Dc + d0;
            const float* fc = g_fcol + (size_t)cI * Dc + d0;
            float4 ra = *(const float4*)(fr);
            float4 rb = *(const float4*)(fr + 4);
            float4 ca = *(const float4*)(fc);
            float4 cb = *(const float4*)(fc + 4);
            dst[0] += ra.x + ca.x; dst[1] += ra.y + ca.y;
            dst[2] += ra.z + ca.z; dst[3] += ra.w + ca.w;
            dst[4] += rb.x + cb.x; dst[5] += rb.y + cb.y;
            dst[6] += rb.z + cb.z; dst[7] += rb.w + cb.w;
        }
    };
    add_spatial(x00, tkA.x, pkA.x);
    add_spatial(x01, tkA.y, pkA.y);
    add_spatial(x10, tkB.x, pkB.x);
    add_spatial(x11, tkB.y, pkB.y);

    // per-lane partial sums for 4 tokens
    float s00 = 0.f, q00 = 0.f, s01 = 0.f, q01 = 0.f;
    float s10 = 0.f, q10 = 0.f, s11 = 0.f, q11 = 0.f;
#pragma unroll
    for (int j = 0; j < 8; ++j) {
        s00 += x00[j]; q00 = fmaf(x00[j], x00[j], q00);
        s01 += x01[j]; q01 = fmaf(x01[j], x01[j], q01);
        s10 += x10[j]; q10 = fmaf(x10[j], x10[j], q10);
        s11 += x11[j]; q11 = fmaf(x11[j], x11[j], q11);
    }
    // 8 independent butterfly chains interleaved — DS pipe stays fed
#pragma unroll
    for (int m = 1; m < 64; m <<= 1) {
        s00 += __shfl_xor(s00, m);
        s01 += __shfl_xor(s01, m);
        s10 += __shfl_xor(s10, m);
        s11 += __shfl_xor(s11, m);
        q00 += __shfl_xor(q00, m);
        q01 += __shfl_xor(q01, m);
        q10 += __shfl_xor(q10, m);
        q11 += __shfl_xor(q11, m);
    }

    const float mu00 = s00 * (1.0f / Dc);
    const float mu01 = s01 * (1.0f / Dc);
    const float mu10 = s10 * (1.0f / Dc);
    const float mu11 = s11 * (1.0f / Dc);
    const float inv00 = rsqrtf(fmaf(-mu00, mu00, q00 * (1.0f / Dc)) + 1e-5f);
    const float inv01 = rsqrtf(fmaf(-mu01, mu01, q01 * (1.0f / Dc)) + 1e-5f);
    const float inv10 = rsqrtf(fmaf(-mu10, mu10, q10 * (1.0f / Dc)) + 1e-5f);
    const float inv11 = rsqrtf(fmaf(-mu11, mu11, q11 * (1.0f / Dc)) + 1e-5f);

    auto store_row = [&](const float* v, float mu, float inv, int base) {
        fvec4 ya, yb;
        ya.x = fmaf((v[0] - mu) * inv, gm[0], bt[0]);
        ya.y = fmaf((v[1] - mu) * inv, gm[1], bt[1]);
        ya.z = fmaf((v[2] - mu) * inv, gm[2], bt[2]);
        ya.w = fmaf((v[3] - mu) * inv, gm[3], bt[3]);
        yb.x = fmaf((v[4] - mu) * inv, gm[4], bt[4]);
        yb.y = fmaf((v[5] - mu) * inv, gm[5], bt[5]);
        yb.z = fmaf((v[6] - mu) * inv, gm[6], bt[6]);
        yb.w = fmaf((v[7] - mu) * inv, gm[7], bt[7]);
        float* op = out + (size_t)base * Dc + d0;
        *(fvec4*)(op + 0) = ya;
        *(fvec4*)(op + 4) = yb;
    };
    // (b0,t),(b0,t+1) contiguous 4KB; (b0+8,t),(b0+8,t+1) contiguous 4KB
    store_row(x00, mu00, inv00, idx00);
    store_row(x01, mu01, inv01, idx00 + 1);
    store_row(x10, mu10, inv10, idx10);
    store_row(x11, mu11, inv11, idx10 + 1);
}

extern "C" void kernel_launch(void* const* d_in, const int* in_sizes, int n_in,
                              void* d_out, int out_size, void* d_ws, size_t ws_size,
                              hipStream_t stream) {
    const int*   ids         = (const int*)d_in[0];
    const float* token_table = (const float*)d_in[1];
    const float* pos_table   = (const float*)d_in[2];
    const float* row_table   = (const float*)d_in[3];
    const float* col_table   = (const float*)d_in[4];
    const float* w_spatial   = (const float*)d_in[5];
    const float* ln_gamma    = (const float*)d_in[6];
    const float* ln_beta     = (const float*)d_in[7];
    float* out = (float*)d_out;

    (void)d_ws; (void)ws_size;   // ws poison is unconditional; we don't add to it

    hipLaunchKernelGGL(scan_pre_kernel, dim3(76), dim3(1024), 0, stream,
                       ids, row_table, col_table, w_spatial);
    hipLaunchKernelGGL(fuse_ln_kernel, dim3(Bc * Tc / 16), dim3(256), 0, stream,
                       ids, token_table, pos_table, ln_gamma, ln_beta, out);
}